// Round 20
// baseline (1515.095 us; speedup 1.0000x reference)
//
#include <hip/hip_runtime.h>
#include <hip/hip_bf16.h>

// Spiking transformer block (Spikformer SSA) on MI355X.
// Layout: [channel][m], m = (b*196+n)*4 + t (time innermost).
//
// CORRECTNESS CONTRACT (r11-r19 PASSED, absmax 0.0 bitwise):
//  - v branch: numpy SSE2-SOP einsum flavor (k_vsse2 byte-identical r18).
//  - out0 GEMMs: in-order ascending-k fp32 FMA chain per element, zero-init;
//    r7 explicit __f*_rn BN/LIF epilogues; x1 = __fadd_rn(x, s) at stage.
//  - bf16 spike storage exact ({0,1}); retiling/swizzle/fusion bitwise-safe
//    (per-element chain order untouched).
// r13: no min-waves hints (AGPR spill). r16: W wave-uniform -> SGPR. r17: XCD
// swizzle + conflict-free staging. r19 lesson: reg-prefetch null at ~19
// waves/CU (TLP already hides latency; stall is barrier cadence) -> r20:
// BK=16 (half the barriers) + q/k fused on one staged X tile (2x FMA density).

#define Cv 384
#define Nv 196
#define Mv 25088        // 128*196 columns
#define HIDv 1536
#define Bv 32
#define Zv 6272         // z = b*196+n
#define TBv 128

// ---- transpose: xp[c*Mv + (b*196+n)*4 + t] = x[((t*32+b)*384+c)*196+n] ----
__global__ __launch_bounds__(256) void k_transpose_in(const float* __restrict__ x,
                                                      float* __restrict__ xp)
{
    int idx = blockIdx.x * 256 + threadIdx.x;
    int c   = idx / Mv;
    int rem = idx - c * Mv;
    int z = rem >> 2, t = rem & 3;
    int b = z / Nv, n = z - b * Nv;
    xp[idx] = x[((size_t)(t * Bv + b) * Cv + c) * Nv + n];
}

// ---- row loader: one X row (4 floats at c1) into regs ----------------------
template<int XBF16, int SADD>
__device__ __forceinline__ void g5_row(const void* __restrict__ Xv,
                                       const __hip_bfloat16* __restrict__ Xs,
                                       int row, int c1, int m0, float* xf)
{
    if (XBF16) {
        const unsigned short* Xb = (const unsigned short*)Xv;
        uint2 u = *(const uint2*)(Xb + (size_t)row * Mv + m0 + c1);
        xf[0] = __uint_as_float((u.x & 0xFFFFu) << 16);
        xf[1] = __uint_as_float(u.x & 0xFFFF0000u);
        xf[2] = __uint_as_float((u.y & 0xFFFFu) << 16);
        xf[3] = __uint_as_float(u.y & 0xFFFF0000u);
    } else {
        const float* Xf = (const float*)Xv;
        float4 xa = *(const float4*)(Xf + (size_t)row * Mv + m0 + c1);
        xf[0]=xa.x; xf[1]=xa.y; xf[2]=xa.z; xf[3]=xa.w;
        if (SADD) {
            const unsigned short* Sb = (const unsigned short*)Xs;
            uint2 u = *(const uint2*)(Sb + (size_t)row * Mv + m0 + c1);
            xf[0] = __fadd_rn(xf[0], (u.x & 0xFFFFu)      ? 1.0f : 0.0f);
            xf[1] = __fadd_rn(xf[1], (u.x & 0xFFFF0000u) ? 1.0f : 0.0f);
            xf[2] = __fadd_rn(xf[2], (u.y & 0xFFFFu)      ? 1.0f : 0.0f);
            xf[3] = __fadd_rn(xf[3], (u.y & 0xFFFF0000u) ? 1.0f : 0.0f);
        }
    }
}

// ---- r7 explicit BN/LIF epilogue (bitwise-proven) --------------------------
__device__ __forceinline__ void g5_epi_spike(const float* acc4, const float* bias,
                                             const float* bnp, int bnC, int o,
                                             int BIAS, unsigned short* pks)
{
    float inv = __fdiv_rn(1.0f, __fsqrt_rn(__fadd_rn(bnp[3*bnC + o], 1e-5f)));
    float scl = __fmul_rn(bnp[o], inv);
    float mu  = bnp[2*bnC + o];
    float be  = bnp[bnC + o];
    float mem = 0.0f;
    #pragma unroll
    for (int j = 0; j < 4; ++j) {
        float val = acc4[j];
        if (BIAS) val = __fadd_rn(val, bias[o]);
        float bn = __fadd_rn(__fmul_rn(__fsub_rn(val, mu), scl), be);
        mem = __fadd_rn(mem, __fmul_rn(__fsub_rn(bn, mem), 0.5f));
        int s = (mem > 1.0f);
        mem = s ? 0.0f : mem;
        pks[j] = s ? 0x3F80 : 0;
    }
}

// ---- W-uniform GEMM, XCD-swizzled, BK=16 -----------------------------------
// Per-element chain bitwise == r4 flavor: acc = fmaf(W[o][k], X[k][m], acc),
// k ascending, zero-init. W wave-uniform -> SGPR. 4 waves x 8 o, lane = 4 m.
template<int XBF16, int SADD, int BIAS, int EPI>
__global__ __launch_bounds__(256) void k_gemm5(const float* __restrict__ W,
                                               const void* __restrict__ Xv,
                                               const __hip_bfloat16* __restrict__ Xs,
                                               const float* __restrict__ bias,
                                               const float* __restrict__ bnp,
                                               int bnC,
                                               void* __restrict__ Y,
                                               int K, int NO)
{
    __shared__ float sX[16][256];   // 16KB
    int id    = blockIdx.x;
    int chunk = gridDim.x >> 3;                            // nwg % 8 == 0
    int idp   = (id & 7) * chunk + (id >> 3);
    int m0    = (idp / NO) * 256;
    int tid  = threadIdx.x;
    int lane = tid & 63;
    int wid  = __builtin_amdgcn_readfirstlane(tid >> 6);
    int ob   = (idp % NO) * 32 + wid * 8;                  // scalar o-base
    int mL   = m0 + lane * 4;
    int r1   = tid >> 6;            // staging rows r1 + {0,4,8,12}
    int c1   = (tid & 63) * 4;      // consecutive 16B: conflict-free

    float acc[8][4];
    #pragma unroll
    for (int i = 0; i < 8; ++i)
        #pragma unroll
        for (int j = 0; j < 4; ++j) acc[i][j] = 0.0f;

    for (int k0 = 0; k0 < K; k0 += 16) {
        float xf[4][4];
        #pragma unroll
        for (int qq = 0; qq < 4; ++qq)
            g5_row<XBF16, SADD>(Xv, Xs, k0 + r1 + qq*4, c1, m0, xf[qq]);
        __syncthreads();
        #pragma unroll
        for (int qq = 0; qq < 4; ++qq)
            *(float4*)&sX[r1 + qq*4][c1] = *(float4*)&xf[qq][0];
        __syncthreads();
        const float* Wb = W + (size_t)ob * K + k0;     // scalar base
        #pragma unroll
        for (int kk = 0; kk < 16; ++kk) {
            float4 xq = *(const float4*)&sX[kk][lane * 4];
            float xv[4] = {xq.x, xq.y, xq.z, xq.w};
            #pragma unroll
            for (int i = 0; i < 8; ++i) {
                float wv = Wb[(size_t)i * K + kk];      // scalar load (SGPR)
                #pragma unroll
                for (int j = 0; j < 4; ++j)
                    acc[i][j] = fmaf(wv, xv[j], acc[i][j]);
            }
        }
    }

    #pragma unroll
    for (int i = 0; i < 8; ++i) {
        int o = ob + i;
        if (EPI == 0) {         // fp32 out + plain bias (r4 flavor)
            float bb = BIAS ? bias[o] : 0.0f;
            float4 r;
            r.x = acc[i][0] + bb; r.y = acc[i][1] + bb;
            r.z = acc[i][2] + bb; r.w = acc[i][3] + bb;
            *(float4*)((float*)Y + (size_t)o * Mv + mL) = r;
        } else {
            ushort4 pk;
            g5_epi_spike(acc[i], bias, bnp, bnC, o, BIAS, (unsigned short*)&pk);
            *(ushort4*)((unsigned short*)Y + (size_t)o * Mv + mL) = pk;
        }
    }
}

// ---- fused q+k GEMM: one staged X tile, two SGPR W panels, 2x density ------
// Both chains bitwise == r4 flavor (independent accumulators, same order).
__global__ __launch_bounds__(256) void k_gemmqk(const float* __restrict__ Wq,
                                                const float* __restrict__ Wk,
                                                const float* __restrict__ X,
                                                const float* __restrict__ bnp,
                                                __hip_bfloat16* __restrict__ Yq,
                                                __hip_bfloat16* __restrict__ Yk)
{
    __shared__ float sX[16][256];   // 16KB
    int id    = blockIdx.x;
    int chunk = gridDim.x >> 3;
    int idp   = (id & 7) * chunk + (id >> 3);
    int m0    = (idp / 12) * 256;
    int tid  = threadIdx.x;
    int lane = tid & 63;
    int wid  = __builtin_amdgcn_readfirstlane(tid >> 6);
    int ob   = (idp % 12) * 32 + wid * 8;
    int mL   = m0 + lane * 4;
    int r1   = tid >> 6;
    int c1   = (tid & 63) * 4;

    float accq[8][4], acck[8][4];
    #pragma unroll
    for (int i = 0; i < 8; ++i)
        #pragma unroll
        for (int j = 0; j < 4; ++j) { accq[i][j] = 0.0f; acck[i][j] = 0.0f; }

    for (int k0 = 0; k0 < Cv; k0 += 16) {
        float xf[4][4];
        #pragma unroll
        for (int qq = 0; qq < 4; ++qq)
            g5_row<0,0>(X, nullptr, k0 + r1 + qq*4, c1, m0, xf[qq]);
        __syncthreads();
        #pragma unroll
        for (int qq = 0; qq < 4; ++qq)
            *(float4*)&sX[r1 + qq*4][c1] = *(float4*)&xf[qq][0];
        __syncthreads();
        const float* Wqb = Wq + (size_t)ob * Cv + k0;
        const float* Wkb = Wk + (size_t)ob * Cv + k0;
        #pragma unroll
        for (int kk = 0; kk < 16; ++kk) {
            float4 xq = *(const float4*)&sX[kk][lane * 4];
            float xv[4] = {xq.x, xq.y, xq.z, xq.w};
            #pragma unroll
            for (int i = 0; i < 8; ++i) {
                float wq = Wqb[(size_t)i * Cv + kk];
                float wk = Wkb[(size_t)i * Cv + kk];
                #pragma unroll
                for (int j = 0; j < 4; ++j) {
                    accq[i][j] = fmaf(wq, xv[j], accq[i][j]);
                    acck[i][j] = fmaf(wk, xv[j], acck[i][j]);
                }
            }
        }
    }

    #pragma unroll
    for (int i = 0; i < 8; ++i) {
        int o = ob + i;
        ushort4 pkq, pkk;
        g5_epi_spike(accq[i], nullptr, bnp,          Cv, o, 0, (unsigned short*)&pkq);
        g5_epi_spike(acck[i], nullptr, bnp + 4*Cv,   Cv, o, 0, (unsigned short*)&pkk);
        *(ushort4*)((unsigned short*)Yq + (size_t)o * Mv + mL) = pkq;
        *(ushort4*)((unsigned short*)Yk + (size_t)o * Mv + mL) = pkk;
    }
}

// ---- V branch: SSE2-SOP GEMM (byte-identical r18) --------------------------
__global__ __launch_bounds__(256) void k_vsse2(const float* __restrict__ W,
                                               const float* __restrict__ X,
                                               const float* __restrict__ bnp,
                                               __hip_bfloat16* __restrict__ Y)
{
    __shared__ float sW[32][68];
    __shared__ float sX[32][64];
    int id    = blockIdx.x;
    int chunk = gridDim.x >> 3;
    int idp   = (id & 7) * chunk + (id >> 3);
    int m0    = (idp / 6) * 64;
    int o0    = (idp % 6) * 64;
    int tid = threadIdx.x;
    int to = tid >> 4, tm = tid & 15;

    float acc[4][4][4];
    #pragma unroll
    for (int s = 0; s < 4; ++s)
        #pragma unroll
        for (int op = 0; op < 4; ++op)
            #pragma unroll
            for (int e = 0; e < 4; ++e) acc[s][op][e] = 0.0f;

    int wq_o = tid >> 3, wq_c = tid & 7;
    int xs_r = tid >> 3, xs_c = (tid & 7) * 8;

    for (int blk = 0; blk < 12; ++blk) {
        int k0 = blk * 32;
        __syncthreads();
        {
            float4 w4 = *(const float4*)(W + (size_t)(o0 + wq_o) * Cv + k0 + wq_c*4);
            sW[wq_c*4+0][wq_o] = w4.x;
            sW[wq_c*4+1][wq_o] = w4.y;
            sW[wq_c*4+2][wq_o] = w4.z;
            sW[wq_c*4+3][wq_o] = w4.w;
            float4 w5 = *(const float4*)(W + (size_t)(o0 + 32 + wq_o) * Cv + k0 + wq_c*4);
            sW[wq_c*4+0][32 + wq_o] = w5.x;
            sW[wq_c*4+1][32 + wq_o] = w5.y;
            sW[wq_c*4+2][32 + wq_o] = w5.z;
            sW[wq_c*4+3][32 + wq_o] = w5.w;
        }
        {
            const float* Xp = X + (size_t)(k0 + xs_r) * Mv + m0 + xs_c;
            *(float4*)&sX[xs_r][xs_c]     = *(const float4*)(Xp);
            *(float4*)&sX[xs_r][xs_c + 4] = *(const float4*)(Xp + 4);
        }
        __syncthreads();
        #pragma unroll
        for (int j = 0; j < 8; ++j) {
            #pragma unroll
            for (int s = 0; s < 4; ++s) {
                int kk = j * 4 + s;
                float4 w4 = *(const float4*)&sW[kk][to*4];
                float4 x4 = *(const float4*)&sX[kk][tm*4];
                float wv[4] = {w4.x, w4.y, w4.z, w4.w};
                float xv[4] = {x4.x, x4.y, x4.z, x4.w};
                #pragma unroll
                for (int op = 0; op < 4; ++op)
                    #pragma unroll
                    for (int e = 0; e < 4; ++e)
                        acc[s][op][e] = __fadd_rn(acc[s][op][e],
                                                  __fmul_rn(wv[op], xv[e]));
            }
        }
    }

    #pragma unroll
    for (int op = 0; op < 4; ++op) {
        int o = o0 + to*4 + op;
        float inv = __fdiv_rn(1.0f, __fsqrt_rn(__fadd_rn(bnp[3*Cv + o], 1e-5f)));
        float sc  = __fmul_rn(bnp[o], inv);
        float mu  = bnp[2*Cv + o];
        float be  = bnp[Cv + o];
        float mem = 0.0f;
        ushort4 pk;
        unsigned short* pks = (unsigned short*)&pk;
        #pragma unroll
        for (int e = 0; e < 4; ++e) {
            float tot = __fadd_rn(__fadd_rn(acc[0][op][e], acc[2][op][e]),
                                  __fadd_rn(acc[1][op][e], acc[3][op][e]));
            float bn = __fadd_rn(__fmul_rn(__fsub_rn(tot, mu), sc), be);
            mem = __fadd_rn(mem, __fmul_rn(__fsub_rn(bn, mem), 0.5f));
            int s = (mem > 1.0f);
            mem = s ? 0.0f : mem;
            pks[e] = s ? 0x3F80 : 0;
        }
        *(ushort4*)((unsigned short*)Y + (size_t)o * Mv + m0 + tm * 4) = pk;
    }
}

// ---- attention per (h, tbl): popcount QK^T, exact fp32 PV ------------------
__global__ __launch_bounds__(256) void k_attn(const __hip_bfloat16* __restrict__ qs,
                                              const __hip_bfloat16* __restrict__ ks,
                                              const __hip_bfloat16* __restrict__ vs,
                                              float* __restrict__ o_chan,
                                              float* __restrict__ v_out)
{
    int h = blockIdx.x, tbl = blockIdx.y;
    int t = tbl >> 5, b = tbl & 31;
    int tid = threadIdx.x;
    __shared__ unsigned kmask[196];
    __shared__ float vf[196][36];
    size_t chb  = (size_t)h * 32 * Mv;
    size_t colb = (size_t)b * Nv * 4 + t;

    for (int e = tid; e < Nv * 32; e += 256) {
        int dd = e / Nv, n = e - dd * Nv;
        vf[n][dd] = __bfloat162float(vs[chb + (size_t)dd * Mv + colb + (size_t)n * 4]);
    }
    unsigned qm = 0;
    if (tid < Nv) {
        unsigned km = 0;
        #pragma unroll
        for (int dd = 0; dd < 32; ++dd) {
            size_t off = chb + (size_t)dd * Mv + colb + (size_t)tid * 4;
            km |= (__bfloat162float(ks[off]) > 0.5f ? 1u : 0u) << dd;
            qm |= (__bfloat162float(qs[off]) > 0.5f ? 1u : 0u) << dd;
        }
        kmask[tid] = km;
    }
    __syncthreads();
    for (int e = tid; e < Nv * 32; e += 256) {
        int n = e >> 5, dd = e & 31;
        v_out[((size_t)(tbl * 12 + h) * Nv + n) * 32 + dd] = vf[n][dd];
    }
    if (tid < Nv) {
        float acc[32] = {};
        for (int nk = 0; nk < Nv; ++nk) {
            float a = (float)__popc(qm & kmask[nk]) * 0.125f;
            #pragma unroll
            for (int dd = 0; dd < 32; ++dd) acc[dd] += a * vf[nk][dd];
        }
        #pragma unroll
        for (int dd = 0; dd < 32; ++dd)
            o_chan[chb + (size_t)dd * Mv + colb + (size_t)tid * 4] = acc[dd];
    }
}

// ---- attn LIF (thr=0.5): exact (dyadic grid) -------------------------------
__global__ __launch_bounds__(256) void k_attnlif(float* __restrict__ o)
{
    int idx = blockIdx.x * 256 + threadIdx.x;
    size_t base = (size_t)idx * 4;
    float4 v = *(const float4*)(o + base);
    float xi[4] = {v.x, v.y, v.z, v.w};
    float s4[4];
    float mem = 0.f;
    #pragma unroll
    for (int t = 0; t < 4; ++t) {
        mem = mem + (xi[t] - mem) * 0.5f;
        s4[t] = (mem > 0.5f) ? 1.0f : 0.0f;
        mem *= (1.0f - s4[t]);
    }
    float4 r; r.x = s4[0]; r.y = s4[1]; r.z = s4[2]; r.w = s4[3];
    *(float4*)(o + base) = r;
}

// ---- fc2 BN+LIF + out = x + s_proj + s_fc2 (byte-identical r16) ------------
__global__ __launch_bounds__(256) void k_final(const float* __restrict__ h2,
                                               const float* __restrict__ bnp,
                                               const float* __restrict__ x,
                                               const __hip_bfloat16* __restrict__ s_proj,
                                               float* __restrict__ out)
{
    int idx = blockIdx.x * 256 + threadIdx.x;   // (c, z)
    int c = idx / Zv;
    int z = idx - c * Zv;
    int b = z / Nv, n = z - b * Nv;
    float gamma = bnp[c], beta = bnp[Cv+c], mean = bnp[2*Cv+c], var = bnp[3*Cv+c];
    float scale = gamma / sqrtf(var + 1e-5f);
    size_t base = (size_t)idx * 4;
    float4 hv = *(const float4*)(h2 + base);
    float xi[4] = {hv.x, hv.y, hv.z, hv.w};
    ushort4 sp4 = *(const ushort4*)((const unsigned short*)s_proj + base);
    unsigned short* sps = (unsigned short*)&sp4;
    float mem = 0.f;
    #pragma unroll
    for (int t = 0; t < 4; ++t) {
        float bnv = (xi[t] - mean) * scale + beta;
        mem = mem + (bnv - mem) * 0.5f;
        float s = (mem > 1.0f) ? 1.0f : 0.0f;
        mem *= (1.0f - s);
        size_t oidx = ((size_t)(t * Bv + b) * Cv + c) * Nv + n;
        float sproj = sps[t] ? 1.0f : 0.0f;
        out[oidx] = x[oidx] + sproj + s;
    }
}

extern "C" void kernel_launch(void* const* d_in, const int* in_sizes, int n_in,
                              void* d_out, int out_size, void* d_ws, size_t ws_size,
                              hipStream_t stream)
{
    const float* x       = (const float*)d_in[0];
    const float* qkvp_w  = (const float*)d_in[1];
    const float* qkvp_bn = (const float*)d_in[2];
    const float* fc1_w   = (const float*)d_in[3];
    const float* fc1_b   = (const float*)d_in[4];
    const float* fc1_bn  = (const float*)d_in[5];
    const float* fc2_w   = (const float*)d_in[6];
    const float* fc2_b   = (const float*)d_in[7];
    const float* fc2_bn  = (const float*)d_in[8];

    float* out1 = (float*)d_out;                    // x_out fp32
    float* out2 = out1 + (size_t)TBv * Cv * Nv;     // v fp32

    const size_t S  = (size_t)Cv * Mv;
    const size_t S4 = S * 4;
    if (ws_size < 4 * S4) return;

    char* wb = (char*)d_ws;
    float* xp            = (float*)wb;                          // @0 (until fc1)
    float* obuf          = (float*)(wb + S4);                   // @1: attn o
    __hip_bfloat16* qs   = (__hip_bfloat16*)(wb + 2*S4);        // @2.0
    __hip_bfloat16* ks   = (__hip_bfloat16*)(wb + 2*S4 + S4/2); // @2.5
    __hip_bfloat16* vs   = (__hip_bfloat16*)(wb + 3*S4);        // @3.0
    __hip_bfloat16* s_pr = (__hip_bfloat16*)(wb + 3*S4 + S4/2); // @3.5
    __hip_bfloat16* H    = (__hip_bfloat16*)(wb + S4);          // @1.0-3.0 fc1 spikes
    float* h2            = (float*)wb;                          // @0 (xp dead)

    k_transpose_in<<<(int)(S/256), 256, 0, stream>>>(x, xp);

    // q + k fused: one staged X tile, two W panels  (nwg=1176, NO=12)
    k_gemmqk<<<1176, 256, 0, stream>>>(qkvp_w, qkvp_w + (size_t)Cv*Cv, xp,
                                       qkvp_bn, qs, ks);
    // v: SSE2-SOP flavor (byte-identical, nwg=2352)
    k_vsse2<<<2352, 256, 0, stream>>>(qkvp_w + (size_t)2*Cv*Cv, xp,
                                      qkvp_bn + (size_t)2*4*Cv, vs);

    k_attn<<<dim3(12, 128), 256, 0, stream>>>(qs, ks, vs, obuf, out2);
    k_attnlif<<<(int)(S/1024), 256, 0, stream>>>(obuf);

    // proj: GEMM + fused r7 BN/LIF -> s_proj  (nwg=1176, NO=12)
    k_gemm5<0,0,0,1><<<1176, 256, 0, stream>>>(
        qkvp_w + (size_t)3*Cv*Cv, obuf, nullptr, nullptr, qkvp_bn + 3*4*Cv, Cv, s_pr, Cv, 12);

    // fc1: GEMM over (xp + s_proj) + bias + BN/LIF -> H spikes  (nwg=4704, NO=48)
    k_gemm5<0,1,1,1><<<4704, 256, 0, stream>>>(
        fc1_w, xp, s_pr, fc1_b, fc1_bn, HIDv, H, Cv, 48);

    // fc2: GEMM from bf16 spikes + bias -> h2 fp32  (nwg=1176, NO=12)
    k_gemm5<1,0,1,0><<<1176, 256, 0, stream>>>(
        fc2_w, H, nullptr, fc2_b, nullptr, 0, h2, HIDv, 12);

    k_final<<<(int)(S/1024), 256, 0, stream>>>(h2, fc2_bn, x, s_pr, out1);
}

// Round 21
// 1194.074 us; speedup vs baseline: 1.2688x; 1.2688x over previous
//
#include <hip/hip_runtime.h>
#include <hip/hip_bf16.h>

// Spiking transformer block (Spikformer SSA) on MI355X.
// Layout: [channel][m], m = (b*196+n)*4 + t (time innermost).
//
// CORRECTNESS CONTRACT (r11-r20 PASSED, absmax 0.0 bitwise):
//  - v branch: numpy SSE2-SOP einsum flavor (k_vsse2 byte-identical r18).
//  - out0 GEMMs: in-order ascending-k fp32 FMA chain per element, zero-init;
//    r7 explicit __f*_rn BN/LIF epilogues; x1 = __fadd_rn(x, s) at stage.
//  - bf16 spike storage exact ({0,1}).
// Ladder: r18 = 1192us. r19 reg-prefetch = 1226 (null at ~19 waves/CU).
// r20 BK=16 + q/k fusion = 1515 (92 VGPR -> 18% occupancy). Both refuted ->
// THIS IS THE EXACT r18 CONFIGURATION (byte-for-byte revert), which sits ~8%
// above the measured scalar-FMA composite floor (~1190us) = roofline under
// the bitwise-chain constraint (no MFMA possible; fp32 chains pinned by np).

#define Cv 384
#define Nv 196
#define Mv 25088        // 128*196 columns
#define HIDv 1536
#define Bv 32
#define Zv 6272         // z = b*196+n
#define TBv 128

// ---- transpose: xp[c*Mv + (b*196+n)*4 + t] = x[((t*32+b)*384+c)*196+n] ----
__global__ __launch_bounds__(256) void k_transpose_in(const float* __restrict__ x,
                                                      float* __restrict__ xp)
{
    int idx = blockIdx.x * 256 + threadIdx.x;
    int c   = idx / Mv;
    int rem = idx - c * Mv;
    int z = rem >> 2, t = rem & 3;
    int b = z / Nv, n = z - b * Nv;
    xp[idx] = x[((size_t)(t * Bv + b) * Cv + c) * Nv + n];
}

// ---- W-uniform GEMM: 4 waves x 8 o-rows, lane = 4 m, BK=8, XCD-swizzled ----
// Per-element chain bitwise == r4 flavor: acc = fmaf(W[o][k], X[k][m], acc),
// k ascending, zero-init. W wave-uniform -> SGPR. 1D grid, bijective swizzle:
// idp = (id&7)*(nwg/8) + (id>>3); m_tile = idp/NO, o_tile = idp%NO.
template<int XBF16, int SADD, int BIAS, int EPI>
__global__ __launch_bounds__(256) void k_gemm5(const float* __restrict__ W,
                                               const void* __restrict__ Xv,
                                               const __hip_bfloat16* __restrict__ Xs,
                                               const float* __restrict__ bias,
                                               const float* __restrict__ bnp,
                                               int bnC,
                                               void* __restrict__ Y,
                                               int K, int NO)
{
    __shared__ float sX[8][256];    // 8KB
    int id    = blockIdx.x;
    int chunk = gridDim.x >> 3;                            // nwg % 8 == 0
    int idp   = (id & 7) * chunk + (id >> 3);
    int m0    = (idp / NO) * 256;
    int obt   = idp % NO;
    int tid  = threadIdx.x;
    int lane = tid & 63;
    int wid  = __builtin_amdgcn_readfirstlane(tid >> 6);   // wave-uniform
    int ob   = obt * 32 + wid * 8;                         // scalar o-base
    int mL   = m0 + lane * 4;
    int r1   = tid >> 6;            // staging rows r1, r1+4
    int c1   = (tid & 63) * 4;      // consecutive 16B per lane: conflict-free

    float acc[8][4];
    #pragma unroll
    for (int i = 0; i < 8; ++i)
        #pragma unroll
        for (int j = 0; j < 4; ++j) acc[i][j] = 0.0f;

    for (int k0 = 0; k0 < K; k0 += 8) {
        float xfa[4], xfb[4];
        if (XBF16) {
            const unsigned short* Xb = (const unsigned short*)Xv;
            uint2 ua = *(const uint2*)(Xb + (size_t)(k0 + r1) * Mv + m0 + c1);
            uint2 ub = *(const uint2*)(Xb + (size_t)(k0 + r1 + 4) * Mv + m0 + c1);
            xfa[0] = __uint_as_float((ua.x & 0xFFFFu) << 16);
            xfa[1] = __uint_as_float(ua.x & 0xFFFF0000u);
            xfa[2] = __uint_as_float((ua.y & 0xFFFFu) << 16);
            xfa[3] = __uint_as_float(ua.y & 0xFFFF0000u);
            xfb[0] = __uint_as_float((ub.x & 0xFFFFu) << 16);
            xfb[1] = __uint_as_float(ub.x & 0xFFFF0000u);
            xfb[2] = __uint_as_float((ub.y & 0xFFFFu) << 16);
            xfb[3] = __uint_as_float(ub.y & 0xFFFF0000u);
        } else {
            const float* Xf = (const float*)Xv;
            float4 xa = *(const float4*)(Xf + (size_t)(k0 + r1) * Mv + m0 + c1);
            float4 xb = *(const float4*)(Xf + (size_t)(k0 + r1 + 4) * Mv + m0 + c1);
            xfa[0]=xa.x; xfa[1]=xa.y; xfa[2]=xa.z; xfa[3]=xa.w;
            xfb[0]=xb.x; xfb[1]=xb.y; xfb[2]=xb.z; xfb[3]=xb.w;
            if (SADD) {
                const unsigned short* Sb = (const unsigned short*)Xs;
                uint2 ua = *(const uint2*)(Sb + (size_t)(k0 + r1) * Mv + m0 + c1);
                uint2 ub = *(const uint2*)(Sb + (size_t)(k0 + r1 + 4) * Mv + m0 + c1);
                xfa[0] = __fadd_rn(xfa[0], (ua.x & 0xFFFFu)      ? 1.0f : 0.0f);
                xfa[1] = __fadd_rn(xfa[1], (ua.x & 0xFFFF0000u) ? 1.0f : 0.0f);
                xfa[2] = __fadd_rn(xfa[2], (ua.y & 0xFFFFu)      ? 1.0f : 0.0f);
                xfa[3] = __fadd_rn(xfa[3], (ua.y & 0xFFFF0000u) ? 1.0f : 0.0f);
                xfb[0] = __fadd_rn(xfb[0], (ub.x & 0xFFFFu)      ? 1.0f : 0.0f);
                xfb[1] = __fadd_rn(xfb[1], (ub.x & 0xFFFF0000u) ? 1.0f : 0.0f);
                xfb[2] = __fadd_rn(xfb[2], (ub.y & 0xFFFFu)      ? 1.0f : 0.0f);
                xfb[3] = __fadd_rn(xfb[3], (ub.y & 0xFFFF0000u) ? 1.0f : 0.0f);
            }
        }
        __syncthreads();
        *(float4*)&sX[r1][c1]     = *(float4*)&xfa[0];
        *(float4*)&sX[r1 + 4][c1] = *(float4*)&xfb[0];
        __syncthreads();
        const float* Wb = W + (size_t)ob * K + k0;     // scalar base
        #pragma unroll
        for (int kk = 0; kk < 8; ++kk) {
            float4 xq = *(const float4*)&sX[kk][lane * 4];
            float xv[4] = {xq.x, xq.y, xq.z, xq.w};
            #pragma unroll
            for (int i = 0; i < 8; ++i) {
                float wv = Wb[(size_t)i * K + kk];      // scalar load (SGPR)
                #pragma unroll
                for (int j = 0; j < 4; ++j)
                    acc[i][j] = fmaf(wv, xv[j], acc[i][j]);
            }
        }
    }

    #pragma unroll
    for (int i = 0; i < 8; ++i) {
        int o = ob + i;
        if (EPI == 0) {         // fp32 out + plain bias (r4 flavor)
            float bb = BIAS ? bias[o] : 0.0f;
            float4 r;
            r.x = acc[i][0] + bb; r.y = acc[i][1] + bb;
            r.z = acc[i][2] + bb; r.w = acc[i][3] + bb;
            *(float4*)((float*)Y + (size_t)o * Mv + mL) = r;
        } else {                // r7 explicit BN/LIF -> bf16 spikes
            float inv = __fdiv_rn(1.0f, __fsqrt_rn(__fadd_rn(bnp[3*bnC + o], 1e-5f)));
            float scl = __fmul_rn(bnp[o], inv);
            float mu  = bnp[2*bnC + o];
            float be  = bnp[bnC + o];
            float mem = 0.0f;
            ushort4 pk;
            unsigned short* pks = (unsigned short*)&pk;
            #pragma unroll
            for (int j = 0; j < 4; ++j) {
                float val = acc[i][j];
                if (BIAS) val = __fadd_rn(val, bias[o]);
                float bn = __fadd_rn(__fmul_rn(__fsub_rn(val, mu), scl), be);
                mem = __fadd_rn(mem, __fmul_rn(__fsub_rn(bn, mem), 0.5f));
                int s = (mem > 1.0f);
                mem = s ? 0.0f : mem;
                pks[j] = s ? 0x3F80 : 0;
            }
            *(ushort4*)((unsigned short*)Y + (size_t)o * Mv + mL) = pk;
        }
    }
}

// ---- V branch: SSE2-SOP GEMM (r12 body; XCD-swizzled 1D grid, NO=6) --------
__global__ __launch_bounds__(256) void k_vsse2(const float* __restrict__ W,
                                               const float* __restrict__ X,
                                               const float* __restrict__ bnp,
                                               __hip_bfloat16* __restrict__ Y)
{
    __shared__ float sW[32][68];
    __shared__ float sX[32][64];
    int id    = blockIdx.x;
    int chunk = gridDim.x >> 3;
    int idp   = (id & 7) * chunk + (id >> 3);
    int m0    = (idp / 6) * 64;
    int o0    = (idp % 6) * 64;
    int tid = threadIdx.x;
    int to = tid >> 4, tm = tid & 15;

    float acc[4][4][4];
    #pragma unroll
    for (int s = 0; s < 4; ++s)
        #pragma unroll
        for (int op = 0; op < 4; ++op)
            #pragma unroll
            for (int e = 0; e < 4; ++e) acc[s][op][e] = 0.0f;

    int wq_o = tid >> 3, wq_c = tid & 7;
    int xs_r = tid >> 3, xs_c = (tid & 7) * 8;

    for (int blk = 0; blk < 12; ++blk) {
        int k0 = blk * 32;
        __syncthreads();
        {
            float4 w4 = *(const float4*)(W + (size_t)(o0 + wq_o) * Cv + k0 + wq_c*4);
            sW[wq_c*4+0][wq_o] = w4.x;
            sW[wq_c*4+1][wq_o] = w4.y;
            sW[wq_c*4+2][wq_o] = w4.z;
            sW[wq_c*4+3][wq_o] = w4.w;
            float4 w5 = *(const float4*)(W + (size_t)(o0 + 32 + wq_o) * Cv + k0 + wq_c*4);
            sW[wq_c*4+0][32 + wq_o] = w5.x;
            sW[wq_c*4+1][32 + wq_o] = w5.y;
            sW[wq_c*4+2][32 + wq_o] = w5.z;
            sW[wq_c*4+3][32 + wq_o] = w5.w;
        }
        {
            const float* Xp = X + (size_t)(k0 + xs_r) * Mv + m0 + xs_c;
            *(float4*)&sX[xs_r][xs_c]     = *(const float4*)(Xp);
            *(float4*)&sX[xs_r][xs_c + 4] = *(const float4*)(Xp + 4);
        }
        __syncthreads();
        #pragma unroll
        for (int j = 0; j < 8; ++j) {
            #pragma unroll
            for (int s = 0; s < 4; ++s) {
                int kk = j * 4 + s;
                float4 w4 = *(const float4*)&sW[kk][to*4];
                float4 x4 = *(const float4*)&sX[kk][tm*4];
                float wv[4] = {w4.x, w4.y, w4.z, w4.w};
                float xv[4] = {x4.x, x4.y, x4.z, x4.w};
                #pragma unroll
                for (int op = 0; op < 4; ++op)
                    #pragma unroll
                    for (int e = 0; e < 4; ++e)
                        acc[s][op][e] = __fadd_rn(acc[s][op][e],
                                                  __fmul_rn(wv[op], xv[e]));
            }
        }
    }

    #pragma unroll
    for (int op = 0; op < 4; ++op) {
        int o = o0 + to*4 + op;
        float inv = __fdiv_rn(1.0f, __fsqrt_rn(__fadd_rn(bnp[3*Cv + o], 1e-5f)));
        float sc  = __fmul_rn(bnp[o], inv);
        float mu  = bnp[2*Cv + o];
        float be  = bnp[Cv + o];
        float mem = 0.0f;
        ushort4 pk;
        unsigned short* pks = (unsigned short*)&pk;
        #pragma unroll
        for (int e = 0; e < 4; ++e) {
            float tot = __fadd_rn(__fadd_rn(acc[0][op][e], acc[2][op][e]),
                                  __fadd_rn(acc[1][op][e], acc[3][op][e]));
            float bn = __fadd_rn(__fmul_rn(__fsub_rn(tot, mu), sc), be);
            mem = __fadd_rn(mem, __fmul_rn(__fsub_rn(bn, mem), 0.5f));
            int s = (mem > 1.0f);
            mem = s ? 0.0f : mem;
            pks[e] = s ? 0x3F80 : 0;
        }
        *(ushort4*)((unsigned short*)Y + (size_t)o * Mv + m0 + tm * 4) = pk;
    }
}

// ---- attention per (h, tbl): popcount QK^T, exact fp32 PV ------------------
__global__ __launch_bounds__(256) void k_attn(const __hip_bfloat16* __restrict__ qs,
                                              const __hip_bfloat16* __restrict__ ks,
                                              const __hip_bfloat16* __restrict__ vs,
                                              float* __restrict__ o_chan,
                                              float* __restrict__ v_out)
{
    int h = blockIdx.x, tbl = blockIdx.y;
    int t = tbl >> 5, b = tbl & 31;
    int tid = threadIdx.x;
    __shared__ unsigned kmask[196];
    __shared__ float vf[196][36];
    size_t chb  = (size_t)h * 32 * Mv;
    size_t colb = (size_t)b * Nv * 4 + t;

    for (int e = tid; e < Nv * 32; e += 256) {
        int dd = e / Nv, n = e - dd * Nv;
        vf[n][dd] = __bfloat162float(vs[chb + (size_t)dd * Mv + colb + (size_t)n * 4]);
    }
    unsigned qm = 0;
    if (tid < Nv) {
        unsigned km = 0;
        #pragma unroll
        for (int dd = 0; dd < 32; ++dd) {
            size_t off = chb + (size_t)dd * Mv + colb + (size_t)tid * 4;
            km |= (__bfloat162float(ks[off]) > 0.5f ? 1u : 0u) << dd;
            qm |= (__bfloat162float(qs[off]) > 0.5f ? 1u : 0u) << dd;
        }
        kmask[tid] = km;
    }
    __syncthreads();
    for (int e = tid; e < Nv * 32; e += 256) {
        int n = e >> 5, dd = e & 31;
        v_out[((size_t)(tbl * 12 + h) * Nv + n) * 32 + dd] = vf[n][dd];
    }
    if (tid < Nv) {
        float acc[32] = {};
        for (int nk = 0; nk < Nv; ++nk) {
            float a = (float)__popc(qm & kmask[nk]) * 0.125f;
            #pragma unroll
            for (int dd = 0; dd < 32; ++dd) acc[dd] += a * vf[nk][dd];
        }
        #pragma unroll
        for (int dd = 0; dd < 32; ++dd)
            o_chan[chb + (size_t)dd * Mv + colb + (size_t)tid * 4] = acc[dd];
    }
}

// ---- attn LIF (thr=0.5): exact (dyadic grid) -------------------------------
__global__ __launch_bounds__(256) void k_attnlif(float* __restrict__ o)
{
    int idx = blockIdx.x * 256 + threadIdx.x;
    size_t base = (size_t)idx * 4;
    float4 v = *(const float4*)(o + base);
    float xi[4] = {v.x, v.y, v.z, v.w};
    float s4[4];
    float mem = 0.f;
    #pragma unroll
    for (int t = 0; t < 4; ++t) {
        mem = mem + (xi[t] - mem) * 0.5f;
        s4[t] = (mem > 0.5f) ? 1.0f : 0.0f;
        mem *= (1.0f - s4[t]);
    }
    float4 r; r.x = s4[0]; r.y = s4[1]; r.z = s4[2]; r.w = s4[3];
    *(float4*)(o + base) = r;
}

// ---- fc2 BN+LIF + out = x + s_proj + s_fc2 (byte-identical r16) ------------
__global__ __launch_bounds__(256) void k_final(const float* __restrict__ h2,
                                               const float* __restrict__ bnp,
                                               const float* __restrict__ x,
                                               const __hip_bfloat16* __restrict__ s_proj,
                                               float* __restrict__ out)
{
    int idx = blockIdx.x * 256 + threadIdx.x;   // (c, z)
    int c = idx / Zv;
    int z = idx - c * Zv;
    int b = z / Nv, n = z - b * Nv;
    float gamma = bnp[c], beta = bnp[Cv+c], mean = bnp[2*Cv+c], var = bnp[3*Cv+c];
    float scale = gamma / sqrtf(var + 1e-5f);
    size_t base = (size_t)idx * 4;
    float4 hv = *(const float4*)(h2 + base);
    float xi[4] = {hv.x, hv.y, hv.z, hv.w};
    ushort4 sp4 = *(const ushort4*)((const unsigned short*)s_proj + base);
    unsigned short* sps = (unsigned short*)&sp4;
    float mem = 0.f;
    #pragma unroll
    for (int t = 0; t < 4; ++t) {
        float bnv = (xi[t] - mean) * scale + beta;
        mem = mem + (bnv - mem) * 0.5f;
        float s = (mem > 1.0f) ? 1.0f : 0.0f;
        mem *= (1.0f - s);
        size_t oidx = ((size_t)(t * Bv + b) * Cv + c) * Nv + n;
        float sproj = sps[t] ? 1.0f : 0.0f;
        out[oidx] = x[oidx] + sproj + s;
    }
}

extern "C" void kernel_launch(void* const* d_in, const int* in_sizes, int n_in,
                              void* d_out, int out_size, void* d_ws, size_t ws_size,
                              hipStream_t stream)
{
    const float* x       = (const float*)d_in[0];
    const float* qkvp_w  = (const float*)d_in[1];
    const float* qkvp_bn = (const float*)d_in[2];
    const float* fc1_w   = (const float*)d_in[3];
    const float* fc1_b   = (const float*)d_in[4];
    const float* fc1_bn  = (const float*)d_in[5];
    const float* fc2_w   = (const float*)d_in[6];
    const float* fc2_b   = (const float*)d_in[7];
    const float* fc2_bn  = (const float*)d_in[8];

    float* out1 = (float*)d_out;                    // x_out fp32
    float* out2 = out1 + (size_t)TBv * Cv * Nv;     // v fp32

    const size_t S  = (size_t)Cv * Mv;
    const size_t S4 = S * 4;
    if (ws_size < 4 * S4) return;

    char* wb = (char*)d_ws;
    float* xp            = (float*)wb;                          // @0 (until fc1)
    float* obuf          = (float*)(wb + S4);                   // @1: attn o
    __hip_bfloat16* qs   = (__hip_bfloat16*)(wb + 2*S4);        // @2.0
    __hip_bfloat16* ks   = (__hip_bfloat16*)(wb + 2*S4 + S4/2); // @2.5
    __hip_bfloat16* vs   = (__hip_bfloat16*)(wb + 3*S4);        // @3.0
    __hip_bfloat16* s_pr = (__hip_bfloat16*)(wb + 3*S4 + S4/2); // @3.5
    __hip_bfloat16* H    = (__hip_bfloat16*)(wb + S4);          // @1.0-3.0 fc1 spikes
    float* h2            = (float*)wb;                          // @0 (xp dead)

    k_transpose_in<<<(int)(S/256), 256, 0, stream>>>(x, xp);

    // q, k: W-uniform GEMM + fused r7 BN/LIF -> bf16 spikes  (nwg=1176, NO=12)
    k_gemm5<0,0,0,1><<<1176, 256, 0, stream>>>(
        qkvp_w, xp, nullptr, nullptr, qkvp_bn, Cv, qs, Cv, 12);
    k_gemm5<0,0,0,1><<<1176, 256, 0, stream>>>(
        qkvp_w + (size_t)Cv*Cv, xp, nullptr, nullptr, qkvp_bn + 4*Cv, Cv, ks, Cv, 12);
    // v: SSE2-SOP flavor (swizzled grid, nwg=2352, NO=6)
    k_vsse2<<<2352, 256, 0, stream>>>(qkvp_w + (size_t)2*Cv*Cv, xp,
                                      qkvp_bn + (size_t)2*4*Cv, vs);

    k_attn<<<dim3(12, 128), 256, 0, stream>>>(qs, ks, vs, obuf, out2);
    k_attnlif<<<(int)(S/1024), 256, 0, stream>>>(obuf);

    // proj: GEMM + fused r7 BN/LIF -> s_proj
    k_gemm5<0,0,0,1><<<1176, 256, 0, stream>>>(
        qkvp_w + (size_t)3*Cv*Cv, obuf, nullptr, nullptr, qkvp_bn + 3*4*Cv, Cv, s_pr, Cv, 12);

    // fc1: GEMM over (xp + s_proj) + bias + BN/LIF -> H spikes  (nwg=4704, NO=48)
    k_gemm5<0,1,1,1><<<4704, 256, 0, stream>>>(
        fc1_w, xp, s_pr, fc1_b, fc1_bn, HIDv, H, Cv, 48);

    // fc2: GEMM from bf16 spikes + bias -> h2 fp32  (nwg=1176, NO=12)
    k_gemm5<1,0,1,0><<<1176, 256, 0, stream>>>(
        fc2_w, H, nullptr, fc2_b, nullptr, 0, h2, HIDv, 12);

    k_final<<<(int)(S/1024), 256, 0, stream>>>(h2, fc2_bn, x, s_pr, out1);
}